// Round 8
// baseline (58.882 us; speedup 1.0000x reference)
//
#include <hip/hip_runtime.h>

// GlobalAttention: out = softmax_j(scores) @ H
// scores[i,j] = sum_m lrelu(Wh1[i,m]+Wh2[j,m]) * a[m]
// lrelu(t) = 0.6t + 0.4|t|; row-constant part drops in softmax:
// scores'[i,j] = s2[j] + sum_m b[m]*|Wh1[i,m]+Wh2[j,m]|, b = 0.4a.
//
// R8: LDS-pipe-bound fix. R4C4 register tiles (LDS:VALU 1.5x, was 2.25x),
// single-barrier dbuf score loop, LDS region aliasing (P/Hs reuse score bufs),
// kW deleted (kF merges k-halves while staging; VMEM pipe is idle anyway).
// LDS row strides 36/68/132 floats (odd # of 16B quads -> strided-row b128
// reads conflict-free; 2-way aliasing is free).

#define HALF 524288

__device__ __forceinline__ float4 f4add(float4 a, float4 b) {
    return make_float4(a.x + b.x, a.y + b.y, a.z + b.z, a.w + b.w);
}

#define LGKM_BAR() do {                                    \
    __builtin_amdgcn_sched_barrier(0);                     \
    asm volatile("s_waitcnt lgkmcnt(0)" ::: "memory");     \
    __builtin_amdgcn_s_barrier();                          \
    __builtin_amdgcn_sched_barrier(0);                     \
} while (0)

// ---------- K1: Whp[z][i][m] = sum_{k in half z} H[i][k]*Wre[m][k]
// Wre[m][k] = W[m&255][(m>>8)*256+k]. 64i x 32m tiles, k-split 2, full-stage,
// ONE barrier. Grid (16,16,2) = 512 blocks, R4C2.
__global__ __launch_bounds__(256) void k1_gemm_wh(const float* __restrict__ H,
                                                  const float* __restrict__ W,
                                                  float* __restrict__ Whp) {
    __shared__ float As[64 * 132];
    __shared__ float Bs[32 * 132];
    const int bi = blockIdx.x, bm = blockIdx.y, bz = blockIdx.z;
    const int t = threadIdx.x;
    const int ti = t >> 4, tj = t & 15;
    const int i0 = ti * 4;
    const int m0 = bm * 32;
    const int half = bm >> 3;
    const int kbase = bz * 128;
    {
        const int r = t >> 2, c = (t & 3) * 32;
        const float* src = H + (size_t)(bi * 64 + r) * 256 + kbase + c;
#pragma unroll
        for (int q = 0; q < 8; ++q)
            *(float4*)&As[r * 132 + c + q * 4] = *(const float4*)(src + q * 4);
    }
    {
        const int r = t >> 3, c = (t & 7) * 16;
        const float* src =
            W + (size_t)((m0 + r) & 255) * 512 + half * 256 + kbase + c;
#pragma unroll
        for (int q = 0; q < 4; ++q)
            *(float4*)&Bs[r * 132 + c + q * 4] = *(const float4*)(src + q * 4);
    }
    __syncthreads();
    float acc[4][2] = {};
#pragma unroll 8
    for (int k = 0; k < 128; k += 4) {
        float4 a[4], b[2];
#pragma unroll
        for (int r = 0; r < 4; ++r) a[r] = *(const float4*)&As[(i0 + r) * 132 + k];
#pragma unroll
        for (int c = 0; c < 2; ++c)
            b[c] = *(const float4*)&Bs[(tj + 16 * c) * 132 + k];
#pragma unroll
        for (int r = 0; r < 4; ++r)
#pragma unroll
            for (int c = 0; c < 2; ++c) {
                acc[r][c] = fmaf(a[r].x, b[c].x, acc[r][c]);
                acc[r][c] = fmaf(a[r].y, b[c].y, acc[r][c]);
                acc[r][c] = fmaf(a[r].z, b[c].z, acc[r][c]);
                acc[r][c] = fmaf(a[r].w, b[c].w, acc[r][c]);
            }
    }
    float* dst = Whp + (size_t)bz * HALF;
#pragma unroll
    for (int r = 0; r < 4; ++r)
#pragma unroll
        for (int c = 0; c < 2; ++c)
            dst[(size_t)(bi * 64 + i0 + r) * 512 + m0 + tj + 16 * c] = acc[r][c];
}

// ---------- K1b: s2[j] = 0.6 * sum_m a[m]*(Whp0[j][256+m]+Whp1[j][256+m])
__global__ __launch_bounds__(256) void k1b_s2(const float* __restrict__ Whp,
                                              const float* __restrict__ a,
                                              float* __restrict__ s2) {
    const int t = threadIdx.x;
    const int lane = t & 63, w = t >> 6;
    const int row = blockIdx.x * 4 + w;
    const size_t off = (size_t)row * 512 + 256 + lane * 4;
    float4 x0 = *(const float4*)&Whp[off];
    float4 x1 = *(const float4*)&Whp[HALF + off];
    float4 av = *(const float4*)&a[lane * 4];
    float d = (x0.x + x1.x) * av.x + (x0.y + x1.y) * av.y +
              (x0.z + x1.z) * av.z + (x0.w + x1.w) * av.w;
#pragma unroll
    for (int o = 32; o > 0; o >>= 1) d += __shfl_xor(d, o);
    if (lane == 0) s2[row] = 0.6f * d;
}

// ---------- KF: flash block = 64 i x 64 j, R4C4. Grid (16,16) = 256 blocks.
// Score: 8 chunks of 32 m, single-barrier dbuf, k-halves merged on stage.
// PV: 4 chunks of 64 c, prefetched H, single Hs buffer (2 bar/chunk).
__global__ __launch_bounds__(256) void kF_flash(const float* __restrict__ Whp,
                                                const float* __restrict__ a,
                                                const float* __restrict__ s2,
                                                const float* __restrict__ H,
                                                float* __restrict__ avp,
                                                float* __restrict__ mbuf,
                                                float* __restrict__ lbuf) {
    __shared__ float R1[4608];  // score: X1 dbuf [2][64][36]; PV: P [64][68]
    __shared__ float R2[4608];  // score: X2 dbuf [2][64][36]; PV: Hs [64][68]
    __shared__ float bsh[256];
    const int bi = blockIdx.x, bj = blockIdx.y;
    const int t = threadIdx.x;
    const int ti = t >> 4, tj = t & 15;
    const int i0 = ti * 4;
    // score staging (tile 64 x 32, 2 f4/thread, merging two k-halves)
    const int rs = t >> 2, cs = (t & 3) * 8;
    const float* g1 = Whp + (size_t)(bi * 64 + rs) * 512 + cs;
    const float* g2 = Whp + (size_t)(bj * 64 + rs) * 512 + 256 + cs;
    // H staging (tile 64 x 64, 4 f4/thread)
    const int cH = (t & 3) * 16;
    const float* gH = H + (size_t)(bj * 64 + rs) * 256 + cH;

    float4 A0, A1, A2, A3, A4, A5, A6, A7;
    float4 B0, B1, B2, B3, B4, B5, B6, B7;

#define LOADS_A(mc) do {                                     \
    A0 = *(const float4*)(g1 + (mc) * 32);                   \
    A1 = *(const float4*)(g1 + (mc) * 32 + 4);               \
    A2 = *(const float4*)(g1 + HALF + (mc) * 32);            \
    A3 = *(const float4*)(g1 + HALF + (mc) * 32 + 4);        \
    A4 = *(const float4*)(g2 + (mc) * 32);                   \
    A5 = *(const float4*)(g2 + (mc) * 32 + 4);               \
    A6 = *(const float4*)(g2 + HALF + (mc) * 32);            \
    A7 = *(const float4*)(g2 + HALF + (mc) * 32 + 4); } while (0)
#define LOADS_B(mc) do {                                     \
    B0 = *(const float4*)(g1 + (mc) * 32);                   \
    B1 = *(const float4*)(g1 + (mc) * 32 + 4);               \
    B2 = *(const float4*)(g1 + HALF + (mc) * 32);            \
    B3 = *(const float4*)(g1 + HALF + (mc) * 32 + 4);        \
    B4 = *(const float4*)(g2 + (mc) * 32);                   \
    B5 = *(const float4*)(g2 + (mc) * 32 + 4);               \
    B6 = *(const float4*)(g2 + HALF + (mc) * 32);            \
    B7 = *(const float4*)(g2 + HALF + (mc) * 32 + 4); } while (0)
#define WRITES_A(buf) do {                                   \
    *(float4*)&R1[((buf) * 64 + rs) * 36 + cs] = f4add(A0, A2);      \
    *(float4*)&R1[((buf) * 64 + rs) * 36 + cs + 4] = f4add(A1, A3);  \
    *(float4*)&R2[((buf) * 64 + rs) * 36 + cs] = f4add(A4, A6);      \
    *(float4*)&R2[((buf) * 64 + rs) * 36 + cs + 4] = f4add(A5, A7); } while (0)
#define WRITES_B(buf) do {                                   \
    *(float4*)&R1[((buf) * 64 + rs) * 36 + cs] = f4add(B0, B2);      \
    *(float4*)&R1[((buf) * 64 + rs) * 36 + cs + 4] = f4add(B1, B3);  \
    *(float4*)&R2[((buf) * 64 + rs) * 36 + cs] = f4add(B4, B6);      \
    *(float4*)&R2[((buf) * 64 + rs) * 36 + cs + 4] = f4add(B5, B7); } while (0)
#define LOADH_A(cc) do {                                     \
    A0 = *(const float4*)(gH + (cc) * 64);                   \
    A1 = *(const float4*)(gH + (cc) * 64 + 4);               \
    A2 = *(const float4*)(gH + (cc) * 64 + 8);               \
    A3 = *(const float4*)(gH + (cc) * 64 + 12); } while (0)
#define LOADH_B(cc) do {                                     \
    B0 = *(const float4*)(gH + (cc) * 64);                   \
    B1 = *(const float4*)(gH + (cc) * 64 + 4);               \
    B2 = *(const float4*)(gH + (cc) * 64 + 8);               \
    B3 = *(const float4*)(gH + (cc) * 64 + 12); } while (0)
#define WRITEH_A() do {                                      \
    *(float4*)&R2[rs * 68 + cH] = A0;                        \
    *(float4*)&R2[rs * 68 + cH + 4] = A1;                    \
    *(float4*)&R2[rs * 68 + cH + 8] = A2;                    \
    *(float4*)&R2[rs * 68 + cH + 12] = A3; } while (0)
#define WRITEH_B() do {                                      \
    *(float4*)&R2[rs * 68 + cH] = B0;                        \
    *(float4*)&R2[rs * 68 + cH + 4] = B1;                    \
    *(float4*)&R2[rs * 68 + cH + 8] = B2;                    \
    *(float4*)&R2[rs * 68 + cH + 12] = B3; } while (0)

    // prologue
    LOADS_A(0);
    LOADS_B(1);
    float s2v0 = s2[bj * 64 + tj];
    float s2v1 = s2[bj * 64 + tj + 16];
    float s2v2 = s2[bj * 64 + tj + 32];
    float s2v3 = s2[bj * 64 + tj + 48];
    if (t < 64) {
        float4 av = *(const float4*)&a[t * 4];
        *(float4*)&bsh[t * 4] =
            make_float4(0.4f * av.x, 0.4f * av.y, 0.4f * av.z, 0.4f * av.w);
    }
    WRITES_A(0);  // compiler waits only A's loads (counted vmcnt)
    LGKM_BAR();

    float acc[4][4] = {};
#pragma unroll
    for (int mc = 0; mc < 8; ++mc) {
        const int buf = mc & 1;
        // write chunk mc+1 into buf^1 (its readers finished at last barrier)
        if (mc < 7) {
            if (buf == 0) WRITES_B(1); else WRITES_A(0);
        }
        // issue loads of chunk mc+2 into the just-freed set
        if (mc < 6) {
            if (buf == 0) { LOADS_A(mc + 2); } else { LOADS_B(mc + 2); }
        }
#pragma unroll
        for (int k = 0; k < 32; k += 4) {
            float4 x1[4], x2[4];
#pragma unroll
            for (int r = 0; r < 4; ++r)
                x1[r] = *(const float4*)&R1[(buf * 64 + i0 + r) * 36 + k];
#pragma unroll
            for (int c = 0; c < 4; ++c)
                x2[c] = *(const float4*)&R2[(buf * 64 + tj + 16 * c) * 36 + k];
            const float4 bv = *(const float4*)&bsh[mc * 32 + k];
#pragma unroll
            for (int r = 0; r < 4; ++r)
#pragma unroll
                for (int c = 0; c < 4; ++c) {
                    acc[r][c] = fmaf(fabsf(x1[r].x + x2[c].x), bv.x, acc[r][c]);
                    acc[r][c] = fmaf(fabsf(x1[r].y + x2[c].y), bv.y, acc[r][c]);
                    acc[r][c] = fmaf(fabsf(x1[r].z + x2[c].z), bv.z, acc[r][c]);
                    acc[r][c] = fmaf(fabsf(x1[r].w + x2[c].w), bv.w, acc[r][c]);
                }
        }
        LGKM_BAR();
    }

    // add s2
#pragma unroll
    for (int r = 0; r < 4; ++r) {
        acc[r][0] += s2v0; acc[r][1] += s2v1;
        acc[r][2] += s2v2; acc[r][3] += s2v3;
    }
    // issue H chunk 0 now; latency hides under softmax
    LOADH_A(0);
    // local softmax over the 64-j chunk (per row: 4 cols + 16-lane reduce)
    float mmv0, mmv1, mmv2, mmv3, llv0, llv1, llv2, llv3;
#pragma unroll
    for (int r = 0; r < 4; ++r) {
        float mm = fmaxf(fmaxf(acc[r][0], acc[r][1]), fmaxf(acc[r][2], acc[r][3]));
        mm = fmaxf(mm, __shfl_xor(mm, 1));
        mm = fmaxf(mm, __shfl_xor(mm, 2));
        mm = fmaxf(mm, __shfl_xor(mm, 4));
        mm = fmaxf(mm, __shfl_xor(mm, 8));
        float l0 = 0.f;
#pragma unroll
        for (int c = 0; c < 4; ++c) {
            acc[r][c] = __expf(acc[r][c] - mm);
            l0 += acc[r][c];
        }
        l0 += __shfl_xor(l0, 1);
        l0 += __shfl_xor(l0, 2);
        l0 += __shfl_xor(l0, 4);
        l0 += __shfl_xor(l0, 8);
        // P aliases R1 (score X1 readers all done at final score barrier)
#pragma unroll
        for (int c = 0; c < 4; ++c) R1[(i0 + r) * 68 + tj + 16 * c] = acc[r][c];
        if (r == 0) { mmv0 = mm; llv0 = l0; }
        else if (r == 1) { mmv1 = mm; llv1 = l0; }
        else if (r == 2) { mmv2 = mm; llv2 = l0; }
        else { mmv3 = mm; llv3 = l0; }
    }
    LGKM_BAR();  // P visible; also the "readers done" barrier for Hs cc=0

    // PV: avp[bj][i][c] = sum_j P[i][j]*H[j][c], 4 chunks of 64 c
#pragma unroll
    for (int cc = 0; cc < 4; ++cc) {
        if ((cc & 1) == 0) WRITEH_A(); else WRITEH_B();
        if (cc < 3) {
            if ((cc & 1) == 0) { LOADH_B(cc + 1); } else { LOADH_A(cc + 1); }
        }
        LGKM_BAR();  // Hs visible
        float acc2[4][4] = {};
#pragma unroll
        for (int jj = 0; jj < 64; jj += 4) {
            float4 pv[4], h[4];
#pragma unroll
            for (int r = 0; r < 4; ++r)
                pv[r] = *(const float4*)&R1[(i0 + r) * 68 + jj];
#pragma unroll
            for (int q = 0; q < 4; ++q)
                h[q] = *(const float4*)&R2[(jj + q) * 68 + tj * 4];
#pragma unroll
            for (int r = 0; r < 4; ++r) {
                acc2[r][0] = fmaf(pv[r].x, h[0].x, acc2[r][0]);
                acc2[r][1] = fmaf(pv[r].x, h[0].y, acc2[r][1]);
                acc2[r][2] = fmaf(pv[r].x, h[0].z, acc2[r][2]);
                acc2[r][3] = fmaf(pv[r].x, h[0].w, acc2[r][3]);
                acc2[r][0] = fmaf(pv[r].y, h[1].x, acc2[r][0]);
                acc2[r][1] = fmaf(pv[r].y, h[1].y, acc2[r][1]);
                acc2[r][2] = fmaf(pv[r].y, h[1].z, acc2[r][2]);
                acc2[r][3] = fmaf(pv[r].y, h[1].w, acc2[r][3]);
                acc2[r][0] = fmaf(pv[r].z, h[2].x, acc2[r][0]);
                acc2[r][1] = fmaf(pv[r].z, h[2].y, acc2[r][1]);
                acc2[r][2] = fmaf(pv[r].z, h[2].z, acc2[r][2]);
                acc2[r][3] = fmaf(pv[r].z, h[2].w, acc2[r][3]);
                acc2[r][0] = fmaf(pv[r].w, h[3].x, acc2[r][0]);
                acc2[r][1] = fmaf(pv[r].w, h[3].y, acc2[r][1]);
                acc2[r][2] = fmaf(pv[r].w, h[3].z, acc2[r][2]);
                acc2[r][3] = fmaf(pv[r].w, h[3].w, acc2[r][3]);
            }
        }
#pragma unroll
        for (int r = 0; r < 4; ++r) {
            *(float4*)&avp[(size_t)bj * 262144 +
                           (size_t)(bi * 64 + i0 + r) * 256 + cc * 64 + tj * 4] =
                make_float4(acc2[r][0], acc2[r][1], acc2[r][2], acc2[r][3]);
        }
        LGKM_BAR();  // readers done before next Hs overwrite
    }
    if (tj == 0) {
        const int gi = bi * 64 + i0;
        mbuf[bj * 1024 + gi] = mmv0;     lbuf[bj * 1024 + gi] = llv0;
        mbuf[bj * 1024 + gi + 1] = mmv1; lbuf[bj * 1024 + gi + 1] = llv1;
        mbuf[bj * 1024 + gi + 2] = mmv2; lbuf[bj * 1024 + gi + 2] = llv2;
        mbuf[bj * 1024 + gi + 3] = mmv3; lbuf[bj * 1024 + gi + 3] = llv3;
    }
#undef LOADS_A
#undef LOADS_B
#undef WRITES_A
#undef WRITES_B
#undef LOADH_A
#undef LOADH_B
#undef WRITEH_A
#undef WRITEH_B
}

// ---------- KM: merge 16 j-chunks with flash rescaling.
__global__ __launch_bounds__(256) void kM_merge(const float* __restrict__ avp,
                                                const float* __restrict__ mbuf,
                                                const float* __restrict__ lbuf,
                                                float* __restrict__ out) {
    const int t = threadIdx.x;
    const int i = blockIdx.x * 4 + (t >> 6);
    const int c0 = (t & 63) * 4;
    float ms[16], es[16];
    float M = -1e30f;
#pragma unroll
    for (int s = 0; s < 16; ++s) {
        ms[s] = mbuf[s * 1024 + i];
        M = fmaxf(M, ms[s]);
    }
    float L = 0.f;
#pragma unroll
    for (int s = 0; s < 16; ++s) {
        es[s] = __expf(ms[s] - M);
        L = fmaf(es[s], lbuf[s * 1024 + i], L);
    }
    const float inv = 1.0f / L;
    float4 o = make_float4(0.f, 0.f, 0.f, 0.f);
#pragma unroll
    for (int s = 0; s < 16; ++s) {
        float4 p = *(const float4*)&avp[(size_t)s * 262144 + (size_t)i * 256 + c0];
        o.x = fmaf(es[s], p.x, o.x);
        o.y = fmaf(es[s], p.y, o.y);
        o.z = fmaf(es[s], p.z, o.z);
        o.w = fmaf(es[s], p.w, o.w);
    }
    o.x *= inv; o.y *= inv; o.z *= inv; o.w *= inv;
    *(float4*)&out[(size_t)i * 256 + c0] = o;
}

extern "C" void kernel_launch(void* const* d_in, const int* in_sizes, int n_in,
                              void* d_out, int out_size, void* d_ws, size_t ws_size,
                              hipStream_t stream) {
    const float* H = (const float*)d_in[0];
    const float* W = (const float*)d_in[1];
    const float* a = (const float*)d_in[2];
    float* out = (float*)d_out;
    float* ws = (float*)d_ws;

    float* avp = ws;                         // 16 x 262144 floats (16 MB)
    float* Whp = ws + (4u << 20);            // 2 x 524288 floats (4 MB) — live in kF
    float* mbuf = Whp + 2 * HALF;            // 16K floats
    float* lbuf = mbuf + 16384;              // 16K floats
    float* s2 = lbuf + 16384;                // 1K floats

    hipLaunchKernelGGL(k1_gemm_wh, dim3(16, 16, 2), dim3(256), 0, stream, H, W, Whp);
    hipLaunchKernelGGL(k1b_s2, dim3(256), dim3(256), 0, stream, Whp, a, s2);
    hipLaunchKernelGGL(kF_flash, dim3(16, 16), dim3(256), 0, stream, Whp, a, s2, H,
                       avp, mbuf, lbuf);
    hipLaunchKernelGGL(kM_merge, dim3(256), dim3(256), 0, stream, avp, mbuf, lbuf, out);
}